// Round 5
// baseline (149.334 us; speedup 1.0000x reference)
//
#include <hip/hip_runtime.h>

#define N_BATCH   50000
#define N_FEATURE 128
#define DEPTH     9
#define N_TREE    200
#define N_NODE    1023
#define N_OUTPUT  8

#define BPB     64                            // batches per block (lanes)
#define WAVES   8
#define BLOCK   (WAVES * 64)                  // 512 threads
#define TPR     8                             // trees per round (1 per wave)
#define ROUNDS  (N_TREE / TPR)                // 25

// Speculative-chain kernel: VGPR-heavy -> 2 blocks/CU expected. Grid sized for
// capacity 512: 512 full chunk-blocks + 270 surplus chunks split into 2
// half-blocks (rounds 0-12 / 13-24) -> ~1.53 generations.
#define FULL_CHUNKS 512
#define NCHUNK      ((N_BATCH + BPB - 1) / BPB)     // 782
#define TAIL_CHUNKS (NCHUNK - FULL_CHUNKS)          // 270
#define TAIL_BLOCKS (TAIL_CHUNKS * 2)               // 540
#define GRID        (FULL_CHUNKS + TAIL_BLOCKS)     // 1052
#define TAIL_SPLIT_R 13

// Per-wave tree buffer, SHIFT-3 layout:
//   thS[k] = th0[k+3] (k=0..511, 2048 B)  -> grandchildren of node a
//            (nodes 4a+3..4a+6) are ONE 16B-aligned float4 @ ((float4*)thS)[a]
//   fS[k]  = f0[k+3] u8 (512 B)           -> their features are ONE u32 @ 4a
// Tree-top nodes 0..14 never touch LDS: root block via uniform float4/int4
// load, nodes 3..14 via readlane of the prefetch quads (lanes 0..2).
// Staging: lane q loads th0[4q+3..4q+6] / +256 -> 2 ds_write_b128 + 2 b32.
#define TREE_B  2560
#define REC_B   (WAVES * TREE_B)              // 20480

__device__ __forceinline__ float readlane_f(float v, int lane) {
    return __int_as_float(__builtin_amdgcn_readlane(__float_as_int(v), lane));
}
__device__ __forceinline__ unsigned pack4(int4 f) {
    return (f.x & 255) | ((f.y & 255) << 8) | ((f.z & 255) << 16) | ((unsigned)f.w << 24);
}

__global__ __launch_bounds__(BLOCK, 4)        // allow <=128 VGPR, no spills
void tree_kernel(const float* __restrict__ x,
                 const int*   __restrict__ feature,
                 const float* __restrict__ threshold,
                 const float* __restrict__ value,
                 float*       __restrict__ out)
{
    __shared__ float xt[N_FEATURE * BPB];           // 32 KB, xt[f*64+b]: bank = lane%32 (free)
    __shared__ __align__(16) char recbuf[REC_B];    // 20 KB, 8 wave-private 2560B slices

    const int tid = threadIdx.x;
    const int bid = blockIdx.x;
    const int b   = tid & 63;                       // lane = batch within chunk
    const int g   = tid >> 6;                       // wave id: tree g of each round
    char* wbuf = recbuf + g * TREE_B;

    int chunk, r0, r1; bool tail;
    if (bid < FULL_CHUNKS) { chunk = bid; r0 = 0; r1 = ROUNDS; tail = false; }
    else {
        const int t2 = bid - FULL_CHUNKS;
        chunk = FULL_CHUNKS + (t2 >> 1);
        if (t2 & 1) { r0 = TAIL_SPLIT_R; r1 = ROUNDS; }
        else        { r0 = 0;            r1 = TAIL_SPLIT_R; }
        tail = true;
    }

    const float* trow  = threshold + (size_t)(r0 * TPR + g) * N_NODE;
    const int*   frow  = feature   + (size_t)(r0 * TPR + g) * N_NODE;
    const float* vbase = value + (size_t)(r0 * TPR + g) * N_NODE * N_OUTPUT;

    // ---- prime prefetch: quads (nodes 3..514) + root block (nodes 0..3) ----
    float4 tA, tB; int4 fA, fB; float4 rtq; int4 rfq;
    __builtin_memcpy(&tA, trow + 3 + 4 * b,       16);
    __builtin_memcpy(&tB, trow + 3 + 4 * b + 256, 16);
    __builtin_memcpy(&fA, frow + 3 + 4 * b,       16);
    __builtin_memcpy(&fB, frow + 3 + 4 * b + 256, 16);
    __builtin_memcpy(&rtq, trow, 16);               // th0[0..3] (uniform addr, VMEM)
    __builtin_memcpy(&rfq, frow, 16);               // f0[0..3]

    // ---- stage x chunk transposed into LDS (conflict-free via XOR-swizzled R) ----
    {
        const float4* x4 = (const float4*)x;
        float4* R = (float4*)recbuf;                // 16 KB alias (pre-round only)
        #pragma unroll
        for (int rr = 0; rr < 2; ++rr) {
            #pragma unroll
            for (int k = 0; k < 2; ++k) {           // 1024 float4 / 512 thr = 2 iters
                const int j  = tid + k * BLOCK;
                const int bl = j >> 5, f4 = j & 31;
                const int gb = chunk * BPB + rr * 32 + bl;
                float4 v = (gb < N_BATCH) ? x4[(size_t)gb * 32 + f4]
                                          : make_float4(0.f, 0.f, 0.f, 0.f);
                R[bl * 32 + (f4 ^ bl)] = v;
            }
            __syncthreads();
            {
                const int b32 = tid & 31, fc = tid >> 5;   // fc = 0..15
                const int bb = rr * 32 + b32;
                #pragma unroll
                for (int c = 0; c < 2; ++c) {
                    const int f4 = fc * 2 + c;
                    float4 v = R[b32 * 32 + (f4 ^ b32)];
                    xt[(f4 * 4 + 0) * BPB + bb] = v.x;
                    xt[(f4 * 4 + 1) * BPB + bb] = v.y;
                    xt[(f4 * 4 + 2) * BPB + bb] = v.z;
                    xt[(f4 * 4 + 3) * BPB + bb] = v.w;
                }
            }
            __syncthreads();
        }
    }
    // No block barriers until the final reduction: each wave owns wbuf
    // exclusively; per-wave DS program order provides WAR/RAW safety.

    float acc[N_OUTPUT];
    #pragma unroll
    for (int o = 0; o < N_OUTPUT; ++o) acc[o] = 0.f;
    float4 vp0 = make_float4(0.f, 0.f, 0.f, 0.f);   // leaf-value pipeline regs
    float4 vp1 = make_float4(0.f, 0.f, 0.f, 0.f);

    float*         thS = (float*)wbuf;
    unsigned char* fS  = (unsigned char*)(wbuf + 2048);

    for (int r = r0; r < r1; ++r) {
        // ---- extract tree-top to regs/SGPRs (before prefetch overwrites) ----
        const float rt0 = rtq.x, rt1 = rtq.y, rt2 = rtq.z, rt3 = rtq.w;  // th0[0..3]
        const int   rf0 = rfq.x, rf1 = rfq.y, rf2 = rfq.z, rf3 = rfq.w;  // f0[0..3]
        const float t4  = readlane_f(tA.y, 0), t5  = readlane_f(tA.z, 0), t6  = readlane_f(tA.w, 0);
        const float t7  = readlane_f(tA.x, 1), t8  = readlane_f(tA.y, 1),
                    t9  = readlane_f(tA.z, 1), t10 = readlane_f(tA.w, 1);
        const float t11 = readlane_f(tA.x, 2), t12 = readlane_f(tA.y, 2),
                    t13 = readlane_f(tA.z, 2), t14 = readlane_f(tA.w, 2);
        const int f4  = __builtin_amdgcn_readlane(fA.y, 0), f5  = __builtin_amdgcn_readlane(fA.z, 0),
                  f6  = __builtin_amdgcn_readlane(fA.w, 0);
        const int f7  = __builtin_amdgcn_readlane(fA.x, 1), f8  = __builtin_amdgcn_readlane(fA.y, 1),
                  f9  = __builtin_amdgcn_readlane(fA.z, 1), f10 = __builtin_amdgcn_readlane(fA.w, 1);
        const int f11 = __builtin_amdgcn_readlane(fA.x, 2), f12 = __builtin_amdgcn_readlane(fA.y, 2),
                  f13 = __builtin_amdgcn_readlane(fA.z, 2), f14 = __builtin_amdgcn_readlane(fA.w, 2);

        // ---- speculative x-gathers for levels 0-2 (all candidates, pre-s0) ----
        const float xg0 = xt[rf0 * BPB + b];
        const float xg1 = xt[rf1 * BPB + b], xg2 = xt[rf2 * BPB + b];
        const float xg3 = xt[rf3 * BPB + b], xg4 = xt[f4 * BPB + b],
                    xg5 = xt[f5  * BPB + b], xg6 = xt[f6 * BPB + b];

        // ---- stage this round's tree (2 b128 + 2 b32 writes) ----
        ((float4*)thS)[b]        = tA;              // thS[4b..4b+3] = th0[4b+3..6]
        ((float4*)thS)[b + 64]   = tB;
        ((unsigned*)fS)[b]       = pack4(fA);
        ((unsigned*)fS)[b + 64]  = pack4(fB);

        // ---- prefetch next round (regs free after extraction/staging) ----
        if (r + 1 < r1) {
            trow += TPR * N_NODE; frow += TPR * N_NODE;
            __builtin_memcpy(&tA, trow + 3 + 4 * b,       16);
            __builtin_memcpy(&tB, trow + 3 + 4 * b + 256, 16);
            __builtin_memcpy(&fA, frow + 3 + 4 * b,       16);
            __builtin_memcpy(&fB, frow + 3 + 4 * b + 256, 16);
            __builtin_memcpy(&rtq, trow, 16);
            __builtin_memcpy(&rfq, frow, 16);
        }

        // ---- level 0 ----
        const int s0 = xg0 > rt0;
        const int n1 = 1 + s0;                      // 0-idx level-1 node
        // level-3 candidate features (mux by s0) -> 4 speculative gathers
        const int fc0 = s0 ? f11 : f7, fc1 = s0 ? f12 : f8,
                  fc2 = s0 ? f13 : f9, fc3 = s0 ? f14 : f10;
        const float xh0 = xt[fc0 * BPB + b], xh1 = xt[fc1 * BPB + b],
                    xh2 = xt[fc2 * BPB + b], xh3 = xt[fc3 * BPB + b];
        // ---- level 1 (regs) ----
        const float xv1 = s0 ? xg2 : xg1; const float tv1 = s0 ? rt2 : rt1;
        const int s1 = xv1 > tv1; const int n2 = 2 * n1 + 1 + s1;     // 3..6
        const float4   q4  = ((const float4*)thS)[n2];   // th of level-4 cands
        const unsigned fq4 = ((const unsigned*)fS)[n2];  // their features
        // ---- level 2 (regs) ----
        const float xva = s0 ? xg5 : xg3, xvb = s0 ? xg6 : xg4;
        const float tva = s0 ? t5 : rt3,  tvb = s0 ? t6 : t4;
        const float xv2 = s1 ? xvb : xva; const float tv2 = s1 ? tvb : tva;
        const int s2 = xv2 > tv2; const int n3 = 2 * n2 + 1 + s2;     // 7..14
        const float4   q5  = ((const float4*)thS)[n3];
        const unsigned fq5 = ((const unsigned*)fS)[n3];
        // ---- level 3 (regs) ----
        const float ta0 = s0 ? t11 : t7, ta1 = s0 ? t12 : t8,
                    ta2 = s0 ? t13 : t9, ta3 = s0 ? t14 : t10;
        const float tb0 = s1 ? ta2 : ta0, tb1 = s1 ? ta3 : ta1;
        const float xc0 = s1 ? xh2 : xh0, xc1 = s1 ? xh3 : xh1;
        const float tv3 = s2 ? tb1 : tb0; const float xv3 = s2 ? xc1 : xc0;
        const int s3 = xv3 > tv3; const int n4 = 2 * n3 + 1 + s3;     // 15..30
        const float4   q6  = ((const float4*)thS)[n4];
        const unsigned fq6 = ((const unsigned*)fS)[n4];
        // ---- level 4 (quad q4/fq4, select by s2,s3) ----
        const float xj0 = xt[(fq4 & 255) * BPB + b], xj1 = xt[((fq4 >> 8) & 255) * BPB + b],
                    xj2 = xt[((fq4 >> 16) & 255) * BPB + b], xj3 = xt[(fq4 >> 24) * BPB + b];
        const float u0 = s2 ? q4.z : q4.x, u1 = s2 ? q4.w : q4.y;
        const float w0 = s2 ? xj2 : xj0,   w1 = s2 ? xj3 : xj1;
        const float tv4 = s3 ? u1 : u0;    const float xv4 = s3 ? w1 : w0;
        const int s4 = xv4 > tv4; const int n5 = 2 * n4 + 1 + s4;     // 31..62
        const float4   q7  = ((const float4*)thS)[n5];
        const unsigned fq7 = ((const unsigned*)fS)[n5];
        // ---- level 5 (q5/fq5, by s3,s4) ----
        const float xk0 = xt[(fq5 & 255) * BPB + b], xk1 = xt[((fq5 >> 8) & 255) * BPB + b],
                    xk2 = xt[((fq5 >> 16) & 255) * BPB + b], xk3 = xt[(fq5 >> 24) * BPB + b];
        const float u2 = s3 ? q5.z : q5.x, u3 = s3 ? q5.w : q5.y;
        const float w2 = s3 ? xk2 : xk0,   w3 = s3 ? xk3 : xk1;
        const float tv5 = s4 ? u3 : u2;    const float xv5 = s4 ? w3 : w2;
        const int s5 = xv5 > tv5; const int n6 = 2 * n5 + 1 + s5;     // 63..126
        const float4   q8  = ((const float4*)thS)[n6];
        const unsigned fq8 = ((const unsigned*)fS)[n6];
        // ---- level 6 (q6/fq6, by s4,s5) ----
        const float xl0 = xt[(fq6 & 255) * BPB + b], xl1 = xt[((fq6 >> 8) & 255) * BPB + b],
                    xl2 = xt[((fq6 >> 16) & 255) * BPB + b], xl3 = xt[(fq6 >> 24) * BPB + b];
        const float u4 = s4 ? q6.z : q6.x, u5 = s4 ? q6.w : q6.y;
        const float w4 = s4 ? xl2 : xl0,   w5 = s4 ? xl3 : xl1;
        const float tv6 = s5 ? u5 : u4;    const float xv6 = s5 ? w5 : w4;
        const int s6 = xv6 > tv6; const int n7 = 2 * n6 + 1 + s6;
        // ---- level 7 (q7/fq7, by s5,s6) ----
        const float xm0 = xt[(fq7 & 255) * BPB + b], xm1 = xt[((fq7 >> 8) & 255) * BPB + b],
                    xm2 = xt[((fq7 >> 16) & 255) * BPB + b], xm3 = xt[(fq7 >> 24) * BPB + b];
        const float u6 = s5 ? q7.z : q7.x, u7 = s5 ? q7.w : q7.y;
        const float w6 = s5 ? xm2 : xm0,   w7 = s5 ? xm3 : xm1;
        const float tv7 = s6 ? u7 : u6;    const float xv7 = s6 ? w7 : w6;
        const int s7 = xv7 > tv7; const int n8 = 2 * n7 + 1 + s7;
        // ---- level 8 (q8/fq8, by s6,s7) ----
        const float xn0 = xt[(fq8 & 255) * BPB + b], xn1 = xt[((fq8 >> 8) & 255) * BPB + b],
                    xn2 = xt[((fq8 >> 16) & 255) * BPB + b], xn3 = xt[(fq8 >> 24) * BPB + b];
        const float u8 = s6 ? q8.z : q8.x, u9 = s6 ? q8.w : q8.y;
        const float w8 = s6 ? xn2 : xn0,   w9 = s6 ? xn3 : xn1;
        const float tv8 = s7 ? u9 : u8;    const float xv8 = s7 ? w9 : w8;
        const int s8 = xv8 > tv8;
        const int leaf = 2 * n8 + 1 + s8;                 // 0-idx leaf, 511..1022

        // ---- software-pipelined leaf gather: load now, accumulate next round ----
        {
            const float4* vp = (const float4*)(vbase + (size_t)leaf * N_OUTPUT);
            const float4 n0v = vp[0], n1v = vp[1];
            acc[0] += vp0.x; acc[1] += vp0.y; acc[2] += vp0.z; acc[3] += vp0.w;
            acc[4] += vp1.x; acc[5] += vp1.y; acc[6] += vp1.z; acc[7] += vp1.w;
            vp0 = n0v; vp1 = n1v;
        }
        vbase += (size_t)TPR * N_NODE * N_OUTPUT;
    }
    // drain value pipeline (preserves per-round add order)
    acc[0] += vp0.x; acc[1] += vp0.y; acc[2] += vp0.z; acc[3] += vp0.w;
    acc[4] += vp1.x; acc[5] += vp1.y; acc[6] += vp1.z; acc[7] += vp1.w;

    // ---- reduce 8 waves' partials (alias recbuf, stride-9 pad) ----
    __syncthreads();
    float* red = (float*)recbuf;                    // 8*576*4 = 18432 <= 20480
    {
        float* dst = red + (g * 576 + b * 9);
        #pragma unroll
        for (int o = 0; o < N_OUTPUT; ++o) dst[o] = acc[o];
    }
    __syncthreads();
    {
        const int bl = tid >> 3, o = tid & 7;       // 512 threads = 64 batches x 8 outs
        const int bg = chunk * BPB + bl;
        float s = 0.f;
        #pragma unroll
        for (int gg = 0; gg < WAVES; ++gg) s += red[gg * 576 + bl * 9 + o];
        s *= (1.0f / N_TREE);
        if (!tail) {
            out[(size_t)chunk * (BPB * N_OUTPUT) + tid] = s;   // coalesced, exactly once
        } else if (bg < N_BATCH) {
            atomicAdd(out + (size_t)bg * N_OUTPUT + o, s);
        }
    }
}

extern "C" void kernel_launch(void* const* d_in, const int* in_sizes, int n_in,
                              void* d_out, int out_size, void* d_ws, size_t ws_size,
                              hipStream_t stream) {
    const float* x         = (const float*)d_in[0];
    const int*   feature   = (const int*)d_in[1];
    const float* threshold = (const float*)d_in[2];
    const float* value     = (const float*)d_in[5];   // children implied by complete heap layout
    float* out = (float*)d_out;

    // zero the tail-chunk region (atomic accumulation)
    const size_t tail_off = (size_t)FULL_CHUNKS * BPB * N_OUTPUT;
    if ((size_t)out_size > tail_off) {
        hipMemsetAsync(out + tail_off, 0, ((size_t)out_size - tail_off) * sizeof(float), stream);
    }

    tree_kernel<<<dim3(GRID), dim3(BLOCK), 0, stream>>>(x, feature, threshold, value, out);
}

// Round 6
// 131.220 us; speedup vs baseline: 1.1380x; 1.1380x over previous
//
#include <hip/hip_runtime.h>

#define N_BATCH   50000
#define N_FEATURE 128
#define DEPTH     9
#define N_TREE    200
#define N_NODE    1023
#define N_OUTPUT  8

#define BPB     64                            // batches per block (lanes)
#define WAVES   8
#define BLOCK   (WAVES * 64)                  // 512 threads
#define TPR     8                             // trees per round (1 per wave)
#define ROUNDS  (N_TREE / TPR)                // 25

// Grid: 768 monolithic chunk-blocks (3/CU x 256 CU, one clean phase) + 14
// surplus chunks shattered into 25 single-round blocks that backfill.
#define FULL_CHUNKS 768
#define NCHUNK      ((N_BATCH + BPB - 1) / BPB)     // 782
#define TAIL_CHUNKS (NCHUNK - FULL_CHUNKS)          // 14
#define TAIL_SPLIT  ROUNDS
#define TAIL_BLOCKS (TAIL_CHUNKS * TAIL_SPLIT)      // 350
#define GRID        (FULL_CHUNKS + TAIL_BLOCKS)     // 1118

// Per-wave private buffer, 1 tree: shifted heap copy
//   thS[k] = th[k+1] (k=0..511)   [2048 B]   pair(n) = float2 @ thS[2n]
//   fS[k]  = feat[k+1] u8         [512 B]    fpair(n) = u16 @ fS[2n]
// Leaf-value gather is LANE-PAIR COOPERATIVE: lane 2i+h fetches the 16B half
// h of batch i's 32B leaf row (and of batch 32+i's row in a second instr).
// Adjacent lanes hit the same 64B line -> TA coalesces -> half the TCP
// line-lookups of the naive per-lane 2x dwordx4 gather. Leaf indices are
// broadcast to the pair with 2x ds_bpermute. Accumulation order per
// (batch,out) is unchanged -> bit-identical result.
#define TREE_B  2560
#define REC_B   (WAVES * TREE_B)              // 20480

__device__ __forceinline__ float readlane_f(float v, int lane) {
    return __int_as_float(__builtin_amdgcn_readlane(__float_as_int(v), lane));
}
__device__ __forceinline__ unsigned pack4(int4 f) {
    return (f.x & 255) | ((f.y & 255) << 8) | ((f.z & 255) << 16) | ((unsigned)f.w << 24);
}

__global__ __launch_bounds__(BLOCK, 6)        // 6 waves/EU -> 3 blocks/CU, 24 waves/CU
void tree_kernel(const float* __restrict__ x,
                 const int*   __restrict__ feature,
                 const float* __restrict__ threshold,
                 const float* __restrict__ value,
                 float*       __restrict__ out)
{
    __shared__ float xt[N_FEATURE * BPB];           // 32 KB, xt[f*64+b]: bank = lane%32 (free)
    __shared__ __align__(16) char recbuf[REC_B];    // 20 KB, 8 wave-private 2560B slices

    const int tid = threadIdx.x;
    const int bid = blockIdx.x;
    const int b   = tid & 63;                       // lane = batch within chunk
    const int g   = tid >> 6;                       // wave id: tree g of each round
    char* wbuf = recbuf + g * TREE_B;

    // lane-pair mapping for the cooperative leaf gather
    const int h   = b & 1;                          // 16B half selector
    const int bA  = b >> 1;                         // batch for piece A (0..31)
    const int bA4 = bA << 2;                        // bpermute byte index
    const int bB4 = (bA + 32) << 2;                 // batch 32+bA

    int chunk, r0, r1; bool tail;
    if (bid < FULL_CHUNKS) { chunk = bid; r0 = 0; r1 = ROUNDS; tail = false; }
    else {
        const int t2 = bid - FULL_CHUNKS;
        chunk = FULL_CHUNKS + t2 / TAIL_SPLIT;
        r0 = t2 % TAIL_SPLIT; r1 = r0 + 1; tail = true;
    }

    // per-round tree-row bases (kept vector -> vmcnt, not SMEM/lgkm)
    const float* trow  = threshold + (size_t)(r0 * TPR + g) * N_NODE;
    const int*   frow  = feature   + (size_t)(r0 * TPR + g) * N_NODE;
    const float* vbase = value + (size_t)(r0 * TPR + g) * N_NODE * N_OUTPUT;

    // per-lane packed-quad sources: nodes 4q+1..4q+4, q = b and q = b+64
    const float* tq = trow + 1 + 4 * b;
    const int*   fq = frow + 1 + 4 * b;

    // ---- prefetch round-r0 records (4 x dwordx4 + broadcast root) ----
    float4 tA, tB; int4 fA, fB;
    __builtin_memcpy(&tA, tq, 16);
    __builtin_memcpy(&tB, tq + 256, 16);
    __builtin_memcpy(&fA, fq, 16);
    __builtin_memcpy(&fB, fq + 256, 16);
    float th0 = trow[0];                            // uniform addr vector load
    int   f0  = frow[0];

    // ---- stage x chunk transposed into LDS (conflict-free via XOR-swizzled R) ----
    {
        const float4* x4 = (const float4*)x;
        float4* R = (float4*)recbuf;                // 16 KB alias (pre-round only)
        #pragma unroll
        for (int rr = 0; rr < 2; ++rr) {
            #pragma unroll
            for (int k = 0; k < 2; ++k) {           // 1024 float4 / 512 thr = 2 iters
                const int j  = tid + k * BLOCK;
                const int bl = j >> 5, f4 = j & 31;
                const int gb = chunk * BPB + rr * 32 + bl;
                float4 v = (gb < N_BATCH) ? x4[(size_t)gb * 32 + f4]
                                          : make_float4(0.f, 0.f, 0.f, 0.f);
                R[bl * 32 + (f4 ^ bl)] = v;
            }
            __syncthreads();
            {
                const int b32 = tid & 31, fc = tid >> 5;   // fc = 0..15
                const int bb = rr * 32 + b32;
                #pragma unroll
                for (int c = 0; c < 2; ++c) {
                    const int f4 = fc * 2 + c;
                    float4 v = R[b32 * 32 + (f4 ^ b32)];
                    xt[(f4 * 4 + 0) * BPB + bb] = v.x;
                    xt[(f4 * 4 + 1) * BPB + bb] = v.y;
                    xt[(f4 * 4 + 2) * BPB + bb] = v.z;
                    xt[(f4 * 4 + 3) * BPB + bb] = v.w;
                }
            }
            __syncthreads();
        }
    }
    // No block barriers until the final reduction: each wave owns wbuf
    // exclusively; per-wave DS program order provides WAR/RAW safety.

    float acc[N_OUTPUT];                            // [0..3]: batch bA outs 4h..4h+3
    #pragma unroll                                  // [4..7]: batch 32+bA outs 4h..4h+3
    for (int o = 0; o < N_OUTPUT; ++o) acc[o] = 0.f;
    float4 ppA = make_float4(0.f, 0.f, 0.f, 0.f);   // leaf-piece pipeline regs
    float4 ppB = make_float4(0.f, 0.f, 0.f, 0.f);

    float*         thS = (float*)wbuf;
    unsigned char* fS  = (unsigned char*)(wbuf + 2048);

    for (int r = r0; r < r1; ++r) {
        // ---- quad-vector staging: 2 x ds_write_b128 + 2 x ds_write_b32 ----
        ((float4*)thS)[b]      = tA;                // nodes 4b+1..4b+4 -> thS[4b..]
        ((float4*)thS)[b + 64] = tB;                // nodes 4b+257..260
        ((unsigned*)fS)[b]      = pack4(fA);
        ((unsigned*)fS)[b + 64] = pack4(fB);

        // ---- root (broadcast regs) + root children (readlane of lane 0's quad) ----
        const float th0c = th0; const int f0c = f0;
        const float cx0 = readlane_f(tA.x, 0);      // node 1 threshold
        const float cy0 = readlane_f(tA.y, 0);      // node 2 threshold
        const int   fl0 = __builtin_amdgcn_readlane(fA.x, 0);
        const int   fh0 = __builtin_amdgcn_readlane(fA.y, 0);

        if (r + 1 < r1) {                           // prefetch next round (regs now free)
            trow += TPR * N_NODE; frow += TPR * N_NODE;
            tq   += TPR * N_NODE; fq   += TPR * N_NODE;
            __builtin_memcpy(&tA, tq, 16);
            __builtin_memcpy(&tB, tq + 256, 16);
            __builtin_memcpy(&fA, fq, 16);
            __builtin_memcpy(&fB, fq + 256, 16);
            th0 = trow[0]; f0 = frow[0];
        }

        // ---- traverse 1 tree; 1-indexed node m, children th via pair reads ----
        int   m  = 1;
        float th = th0c;
        int   fv = f0c;
        float2 c = make_float2(cx0, cy0);           // children of root (regs)
        int   fl = fl0, fh = fh0;
        #pragma unroll
        for (int d = 0; d < DEPTH; ++d) {
            const float xv = xt[fv * BPB + b];      // only on-chain LDS read
            const int s = (xv > th) ? 1 : 0;        // xval <= split -> left
            m = 2 * m + s;
            if (d < DEPTH - 1) {
                th = s ? c.y : c.x;
                fv = s ? fh : fl;
            }
            if (d < DEPTH - 2) {                    // speculative pair read (m-1 <= 254)
                c = ((float2*)thS)[m - 1];
                const int k2 = ((unsigned short*)fS)[m - 1];
                fl = k2 & 255; fh = k2 >> 8;        // off-chain extraction
            }
        }
        // ---- lane-pair cooperative leaf gather (pipelined to next round) ----
        {
            const int leaf = m - 1;                 // 0-idx leaf, [511,1022]
            const int lA = __builtin_amdgcn_ds_bpermute(bA4, leaf);  // batch bA's leaf
            const int lB = __builtin_amdgcn_ds_bpermute(bB4, leaf);  // batch 32+bA's
            const float4 nA = *(const float4*)(vbase + (size_t)lA * N_OUTPUT + 4 * h);
            const float4 nB = *(const float4*)(vbase + (size_t)lB * N_OUTPUT + 4 * h);
            acc[0] += ppA.x; acc[1] += ppA.y; acc[2] += ppA.z; acc[3] += ppA.w;
            acc[4] += ppB.x; acc[5] += ppB.y; acc[6] += ppB.z; acc[7] += ppB.w;
            ppA = nA; ppB = nB;
        }
        vbase += (size_t)TPR * N_NODE * N_OUTPUT;
    }
    // drain leaf pipeline (preserves per-round add order -> bit-identical)
    acc[0] += ppA.x; acc[1] += ppA.y; acc[2] += ppA.z; acc[3] += ppA.w;
    acc[4] += ppB.x; acc[5] += ppB.y; acc[6] += ppB.z; acc[7] += ppB.w;

    // ---- reduce 8 waves' partials (alias recbuf, stride-9 pad) ----
    __syncthreads();
    float* red = (float*)recbuf;                    // 8*576*4 = 18432 <= 20480
    {
        const int h4 = h * 4;
        float* dstA = red + (g * 576 + bA * 9 + h4);
        float* dstB = red + (g * 576 + (32 + bA) * 9 + h4);
        dstA[0] = acc[0]; dstA[1] = acc[1]; dstA[2] = acc[2]; dstA[3] = acc[3];
        dstB[0] = acc[4]; dstB[1] = acc[5]; dstB[2] = acc[6]; dstB[3] = acc[7];
    }
    __syncthreads();
    {
        const int bl = tid >> 3, o = tid & 7;       // 512 threads = 64 batches x 8 outs
        const int bg = chunk * BPB + bl;
        float s = 0.f;
        #pragma unroll
        for (int gg = 0; gg < WAVES; ++gg) s += red[gg * 576 + bl * 9 + o];
        s *= (1.0f / N_TREE);
        if (!tail) {
            out[(size_t)chunk * (BPB * N_OUTPUT) + tid] = s;   // coalesced, exactly once
        } else if (bg < N_BATCH) {
            atomicAdd(out + (size_t)bg * N_OUTPUT + o, s);
        }
    }
}

extern "C" void kernel_launch(void* const* d_in, const int* in_sizes, int n_in,
                              void* d_out, int out_size, void* d_ws, size_t ws_size,
                              hipStream_t stream) {
    const float* x         = (const float*)d_in[0];
    const int*   feature   = (const int*)d_in[1];
    const float* threshold = (const float*)d_in[2];
    const float* value     = (const float*)d_in[5];   // children implied by complete heap layout
    float* out = (float*)d_out;

    // zero only the tail-chunk region (atomic accumulation); ~27 KB
    const size_t tail_off = (size_t)FULL_CHUNKS * BPB * N_OUTPUT;
    if ((size_t)out_size > tail_off) {
        hipMemsetAsync(out + tail_off, 0, ((size_t)out_size - tail_off) * sizeof(float), stream);
    }

    tree_kernel<<<dim3(GRID), dim3(BLOCK), 0, stream>>>(x, feature, threshold, value, out);
}

// Round 8
// 129.736 us; speedup vs baseline: 1.1511x; 1.0114x over previous
//
#include <hip/hip_runtime.h>

#define N_BATCH   50000
#define N_FEATURE 128
#define DEPTH     9
#define N_TREE    200
#define N_NODE    1023
#define N_OUTPUT  8

#define BPB     64                            // batches per block (lanes)
#define WAVES   8
#define BLOCK   (WAVES * 64)                  // 512 threads
#define TPR     8                             // trees per round (1 per wave)
#define ROUNDS  (N_TREE / TPR)                // 25

// Grid: 768 monolithic chunk-blocks (3/CU x 256 CU, one clean phase) + 14
// surplus chunks shattered into 25 single-round blocks that backfill.
#define FULL_CHUNKS 768
#define NCHUNK      ((N_BATCH + BPB - 1) / BPB)     // 782
#define TAIL_CHUNKS (NCHUNK - FULL_CHUNKS)          // 14
#define TAIL_SPLIT  ROUNDS
#define TAIL_BLOCKS (TAIL_CHUNKS * TAIL_SPLIT)      // 350
#define GRID        (FULL_CHUNKS + TAIL_BLOCKS)     // 1118

// Per-wave private buffer, 1 tree: shifted heap copy
//   thS[k] = th[k+1] (k=0..511)   [2048 B]
//   fS[k]  = feat[k+1] u8         [512 B]    fpair(n) = u16 @ fS[2n]
// Traversal: th of the CHOSEN child via direct ds_read_b32 (index known at
// issue; value consumed only after the next xt gather -> latency slack).
// Only the FEATURE pair is fetched one level early (u16): fv feeds the next
// xt address (critical chain). vs the b64 both-children pair read this is
// ~45% fewer pair-path LDS-port cycles and no random-b64 bank conflicts.
// ORDERING (the round-7 lesson): hardware DS execution is in-order per wave,
// but the COMPILER may reorder independent LDS reads/writes across phase
// boundaries (staging stores are dataflow-independent of traversal loads).
// Two zero-cost compiler fences per round pin the program order:
//   loop-top fence:   prev round's reads  precede  this round's writes (WAR)
//   post-stage fence: this round's writes precede  this round's reads  (RAW)
// Leaf gather: LANE-PAIR COOPERATIVE (V6): lane 2i+h fetches 16B half h of
// batch i's and batch 32+i's 32B leaf rows; indices via 2x ds_bpermute.
#define TREE_B  2560
#define REC_B   (WAVES * TREE_B)              // 20480

__device__ __forceinline__ unsigned pack4(int4 f) {
    return (f.x & 255) | ((f.y & 255) << 8) | ((f.z & 255) << 16) | ((unsigned)f.w << 24);
}

__global__ __launch_bounds__(BLOCK, 6)        // 6 waves/EU -> 3 blocks/CU, 24 waves/CU
void tree_kernel(const float* __restrict__ x,
                 const int*   __restrict__ feature,
                 const float* __restrict__ threshold,
                 const float* __restrict__ value,
                 float*       __restrict__ out)
{
    __shared__ float xt[N_FEATURE * BPB];           // 32 KB, xt[f*64+b]: bank = lane%32 (free)
    __shared__ __align__(16) char recbuf[REC_B];    // 20 KB, 8 wave-private 2560B slices

    const int tid = threadIdx.x;
    const int bid = blockIdx.x;
    const int b   = tid & 63;                       // lane = batch within chunk
    const int g   = tid >> 6;                       // wave id: tree g of each round
    char* wbuf = recbuf + g * TREE_B;

    // lane-pair mapping for the cooperative leaf gather
    const int h   = b & 1;                          // 16B half selector
    const int bA  = b >> 1;                         // batch for piece A (0..31)
    const int bA4 = bA << 2;                        // bpermute byte index
    const int bB4 = (bA + 32) << 2;                 // batch 32+bA

    int chunk, r0, r1; bool tail;
    if (bid < FULL_CHUNKS) { chunk = bid; r0 = 0; r1 = ROUNDS; tail = false; }
    else {
        const int t2 = bid - FULL_CHUNKS;
        chunk = FULL_CHUNKS + t2 / TAIL_SPLIT;
        r0 = t2 % TAIL_SPLIT; r1 = r0 + 1; tail = true;
    }

    // per-round tree-row bases (kept vector -> vmcnt, not SMEM/lgkm)
    const float* trow  = threshold + (size_t)(r0 * TPR + g) * N_NODE;
    const int*   frow  = feature   + (size_t)(r0 * TPR + g) * N_NODE;
    const float* vbase = value + (size_t)(r0 * TPR + g) * N_NODE * N_OUTPUT;

    // per-lane packed-quad sources: nodes 4q+1..4q+4, q = b and q = b+64
    const float* tq = trow + 1 + 4 * b;
    const int*   fq = frow + 1 + 4 * b;

    // ---- prefetch round-r0 records (4 x dwordx4 + broadcast root) ----
    float4 tA, tB; int4 fA, fB;
    __builtin_memcpy(&tA, tq, 16);
    __builtin_memcpy(&tB, tq + 256, 16);
    __builtin_memcpy(&fA, fq, 16);
    __builtin_memcpy(&fB, fq + 256, 16);
    float th0 = trow[0];                            // uniform addr vector load
    int   f0  = frow[0];

    // ---- stage x chunk transposed into LDS (conflict-free via XOR-swizzled R) ----
    {
        const float4* x4 = (const float4*)x;
        float4* R = (float4*)recbuf;                // 16 KB alias (pre-round only)
        #pragma unroll
        for (int rr = 0; rr < 2; ++rr) {
            #pragma unroll
            for (int k = 0; k < 2; ++k) {           // 1024 float4 / 512 thr = 2 iters
                const int j  = tid + k * BLOCK;
                const int bl = j >> 5, f4 = j & 31;
                const int gb = chunk * BPB + rr * 32 + bl;
                float4 v = (gb < N_BATCH) ? x4[(size_t)gb * 32 + f4]
                                          : make_float4(0.f, 0.f, 0.f, 0.f);
                R[bl * 32 + (f4 ^ bl)] = v;
            }
            __syncthreads();
            {
                const int b32 = tid & 31, fc = tid >> 5;   // fc = 0..15
                const int bb = rr * 32 + b32;
                #pragma unroll
                for (int c = 0; c < 2; ++c) {
                    const int f4 = fc * 2 + c;
                    float4 v = R[b32 * 32 + (f4 ^ b32)];
                    xt[(f4 * 4 + 0) * BPB + bb] = v.x;
                    xt[(f4 * 4 + 1) * BPB + bb] = v.y;
                    xt[(f4 * 4 + 2) * BPB + bb] = v.z;
                    xt[(f4 * 4 + 3) * BPB + bb] = v.w;
                }
            }
            __syncthreads();
        }
    }
    // No block barriers until the final reduction: each wave owns wbuf
    // exclusively; HW DS in-order + per-round compiler fences give WAR/RAW.

    float acc[N_OUTPUT];                            // [0..3]: batch bA outs 4h..4h+3
    #pragma unroll                                  // [4..7]: batch 32+bA outs 4h..4h+3
    for (int o = 0; o < N_OUTPUT; ++o) acc[o] = 0.f;
    float4 ppA = make_float4(0.f, 0.f, 0.f, 0.f);   // leaf-piece pipeline regs
    float4 ppB = make_float4(0.f, 0.f, 0.f, 0.f);

    float*         thS = (float*)wbuf;
    unsigned char* fS  = (unsigned char*)(wbuf + 2048);

    for (int r = r0; r < r1; ++r) {
        __asm__ volatile("" ::: "memory");          // WAR fence: prev reads < these writes
        // ---- quad-vector staging: 2 x ds_write_b128 + 2 x ds_write_b32 ----
        ((float4*)thS)[b]      = tA;                // nodes 4b+1..4b+4 -> thS[4b..]
        ((float4*)thS)[b + 64] = tB;                // nodes 4b+257..260
        ((unsigned*)fS)[b]      = pack4(fA);
        ((unsigned*)fS)[b + 64] = pack4(fB);
        __asm__ volatile("" ::: "memory");          // RAW fence: writes < traversal reads

        // ---- root (broadcast regs) + root-children feats (readlane lane 0) ----
        const float th0c = th0; const int f0c = f0;
        const int   fl0 = __builtin_amdgcn_readlane(fA.x, 0);   // feat node 1
        const int   fh0 = __builtin_amdgcn_readlane(fA.y, 0);   // feat node 2

        if (r + 1 < r1) {                           // prefetch next round (regs now free)
            trow += TPR * N_NODE; frow += TPR * N_NODE;
            tq   += TPR * N_NODE; fq   += TPR * N_NODE;
            __builtin_memcpy(&tA, tq, 16);
            __builtin_memcpy(&tB, tq + 256, 16);
            __builtin_memcpy(&fA, fq, 16);
            __builtin_memcpy(&fB, fq + 256, 16);
            th0 = trow[0]; f0 = frow[0];
        }

        // ---- traverse 1 tree; direct child-th b32 reads, early feat pairs ----
        int   m  = 1;                               // 1-indexed node
        float th = th0c;
        int   fv = f0c;
        int   fl = fl0, fh = fh0;                   // feats of m's children
        #pragma unroll
        for (int d = 0; d < DEPTH; ++d) {
            const float xv = xt[fv * BPB + b];      // on-chain LDS read
            const int s = (xv > th) ? 1 : 0;        // xval <= split -> left
            m = 2 * m + s;
            if (d < DEPTH - 1) {
                th = thS[m - 2];                    // chosen child's th (off-chain slack)
                fv = s ? fh : fl;                   // from pair fetched last level (regs)
            }
            if (d < DEPTH - 2) {                    // feats of new m's children, 1 early
                const int k2 = ((unsigned short*)fS)[m - 1];
                fl = k2 & 255; fh = k2 >> 8;
            }
        }
        // ---- lane-pair cooperative leaf gather (pipelined to next round) ----
        {
            const int leaf = m - 1;                 // 0-idx leaf, [511,1022]
            const int lA = __builtin_amdgcn_ds_bpermute(bA4, leaf);  // batch bA's leaf
            const int lB = __builtin_amdgcn_ds_bpermute(bB4, leaf);  // batch 32+bA's
            const float4 nA = *(const float4*)(vbase + (size_t)lA * N_OUTPUT + 4 * h);
            const float4 nB = *(const float4*)(vbase + (size_t)lB * N_OUTPUT + 4 * h);
            acc[0] += ppA.x; acc[1] += ppA.y; acc[2] += ppA.z; acc[3] += ppA.w;
            acc[4] += ppB.x; acc[5] += ppB.y; acc[6] += ppB.z; acc[7] += ppB.w;
            ppA = nA; ppB = nB;
        }
        vbase += (size_t)TPR * N_NODE * N_OUTPUT;
    }
    // drain leaf pipeline (preserves per-round add order -> bit-identical)
    acc[0] += ppA.x; acc[1] += ppA.y; acc[2] += ppA.z; acc[3] += ppA.w;
    acc[4] += ppB.x; acc[5] += ppB.y; acc[6] += ppB.z; acc[7] += ppB.w;

    // ---- reduce 8 waves' partials (alias recbuf, stride-9 pad) ----
    __syncthreads();
    float* red = (float*)recbuf;                    // 8*576*4 = 18432 <= 20480
    {
        const int h4 = h * 4;
        float* dstA = red + (g * 576 + bA * 9 + h4);
        float* dstB = red + (g * 576 + (32 + bA) * 9 + h4);
        dstA[0] = acc[0]; dstA[1] = acc[1]; dstA[2] = acc[2]; dstA[3] = acc[3];
        dstB[0] = acc[4]; dstB[1] = acc[5]; dstB[2] = acc[6]; dstB[3] = acc[7];
    }
    __syncthreads();
    {
        const int bl = tid >> 3, o = tid & 7;       // 512 threads = 64 batches x 8 outs
        const int bg = chunk * BPB + bl;
        float s = 0.f;
        #pragma unroll
        for (int gg = 0; gg < WAVES; ++gg) s += red[gg * 576 + bl * 9 + o];
        s *= (1.0f / N_TREE);
        if (!tail) {
            out[(size_t)chunk * (BPB * N_OUTPUT) + tid] = s;   // coalesced, exactly once
        } else if (bg < N_BATCH) {
            atomicAdd(out + (size_t)bg * N_OUTPUT + o, s);
        }
    }
}

extern "C" void kernel_launch(void* const* d_in, const int* in_sizes, int n_in,
                              void* d_out, int out_size, void* d_ws, size_t ws_size,
                              hipStream_t stream) {
    const float* x         = (const float*)d_in[0];
    const int*   feature   = (const int*)d_in[1];
    const float* threshold = (const float*)d_in[2];
    const float* value     = (const float*)d_in[5];   // children implied by complete heap layout
    float* out = (float*)d_out;

    // zero only the tail-chunk region (atomic accumulation); ~27 KB
    const size_t tail_off = (size_t)FULL_CHUNKS * BPB * N_OUTPUT;
    if ((size_t)out_size > tail_off) {
        hipMemsetAsync(out + tail_off, 0, ((size_t)out_size - tail_off) * sizeof(float), stream);
    }

    tree_kernel<<<dim3(GRID), dim3(BLOCK), 0, stream>>>(x, feature, threshold, value, out);
}